// Round 1
// baseline (2414.374 us; speedup 1.0000x reference)
//
#include <hip/hip_runtime.h>

#define EPS 1e-5f

__device__ __forceinline__ int reflect_idx(int i, int n) {
    if (i < 0) return -i;
    if (i >= n) return 2 * n - 2 - i;
    return i;
}

// ---------------- Level-0 input build: [coords(2), f1(64)] @ 4x66x32x32 ----------------
__global__ void build0_kernel(const float* __restrict__ f1, float* __restrict__ pin) {
    const int B = 4, C = 66, H = 32, W = 32;
    int idx = blockIdx.x * blockDim.x + threadIdx.x;
    int total = B * C * H * W;
    if (idx >= total) return;
    int w = idx % W;
    int h = (idx / W) % H;
    int c = (idx / (W * H)) % C;
    int b = idx / (W * H * C);
    float v;
    if (c == 0)      v = -1.f + 2.f * w / (W - 1);
    else if (c == 1) v = -1.f + 2.f * h / (H - 1);
    else             v = f1[((b * 64 + (c - 2)) * H + h) * W + w];
    pin[idx] = v;
}

// ---------------- Level-1 input build: [coords(2), f0(32), BN(resize2x(pw0))(64)] @ 4x98x64x64 ----
__global__ void build1_kernel(const float* __restrict__ f0, const float* __restrict__ prev,
                              const float* __restrict__ pstats, const float* __restrict__ g,
                              const float* __restrict__ bb, float* __restrict__ pin) {
    const int B = 4, C = 98, H = 64, W = 64, Cf = 32, Hp = 32, Wp = 32, Cp = 64;
    const float invN = 1.f / (B * Hp * Wp);
    int idx = blockIdx.x * blockDim.x + threadIdx.x;
    int total = B * C * H * W;
    if (idx >= total) return;
    int w = idx % W;
    int h = (idx / W) % H;
    int c = (idx / (W * H)) % C;
    int b = idx / (W * H * C);
    float v;
    if (c == 0)      v = -1.f + 2.f * w / (W - 1);
    else if (c == 1) v = -1.f + 2.f * h / (H - 1);
    else if (c < 2 + Cf) v = f0[((b * Cf + (c - 2)) * H + h) * W + w];
    else {
        int o = c - 2 - Cf;
        float sy = (h + 0.5f) * 0.5f - 0.5f;
        float sx = (w + 0.5f) * 0.5f - 0.5f;
        int y0 = (int)floorf(sy), x0 = (int)floorf(sx);
        float fy = sy - y0, fx = sx - x0;
        int y0c = min(max(y0, 0), Hp - 1), y1c = min(max(y0 + 1, 0), Hp - 1);
        int x0c = min(max(x0, 0), Wp - 1), x1c = min(max(x0 + 1, 0), Wp - 1);
        const float* pb = prev + ((size_t)(b * Cp + o) * Hp) * Wp;
        float v00 = pb[y0c * Wp + x0c], v01 = pb[y0c * Wp + x1c];
        float v10 = pb[y1c * Wp + x0c], v11 = pb[y1c * Wp + x1c];
        float raw = v00 * (1 - fy) * (1 - fx) + v01 * (1 - fy) * fx
                  + v10 * fy * (1 - fx) + v11 * fy * fx;
        float m = pstats[2 * o] * invN;
        float var = pstats[2 * o + 1] * invN - m * m;
        float inv = rsqrtf(var + EPS);
        v = (raw - m) * inv * g[o] + bb[o];
    }
    pin[idx] = v;
}

// ---------------- Level-2 input build: [coords(2), x_img(3), BN(resize4x(pw1))(32)] @ 4x37x256x256 ----
__global__ void build2_kernel(const float* __restrict__ ximg, const float* __restrict__ prev,
                              const float* __restrict__ pstats, const float* __restrict__ g,
                              const float* __restrict__ bb, float* __restrict__ pin) {
    const int B = 4, C = 37, H = 256, W = 256, Cf = 3, Hp = 64, Wp = 64, Cp = 32;
    const float invN = 1.f / (B * Hp * Wp);
    int idx = blockIdx.x * blockDim.x + threadIdx.x;
    int total = B * C * H * W;
    if (idx >= total) return;
    int w = idx % W;
    int h = (idx / W) % H;
    int c = (idx / (W * H)) % C;
    int b = idx / (W * H * C);
    float v;
    if (c == 0)      v = -1.f + 2.f * w / (W - 1);
    else if (c == 1) v = -1.f + 2.f * h / (H - 1);
    else if (c < 2 + Cf) v = ximg[((b * Cf + (c - 2)) * H + h) * W + w];
    else {
        int o = c - 2 - Cf;
        float sy = (h + 0.5f) * 0.25f - 0.5f;
        float sx = (w + 0.5f) * 0.25f - 0.5f;
        int y0 = (int)floorf(sy), x0 = (int)floorf(sx);
        float fy = sy - y0, fx = sx - x0;
        int y0c = min(max(y0, 0), Hp - 1), y1c = min(max(y0 + 1, 0), Hp - 1);
        int x0c = min(max(x0, 0), Wp - 1), x1c = min(max(x0 + 1, 0), Wp - 1);
        const float* pb = prev + ((size_t)(b * Cp + o) * Hp) * Wp;
        float v00 = pb[y0c * Wp + x0c], v01 = pb[y0c * Wp + x1c];
        float v10 = pb[y1c * Wp + x0c], v11 = pb[y1c * Wp + x1c];
        float raw = v00 * (1 - fy) * (1 - fx) + v01 * (1 - fy) * fx
                  + v10 * fy * (1 - fx) + v11 * fy * fx;
        float m = pstats[2 * o] * invN;
        float var = pstats[2 * o + 1] * invN - m * m;
        float inv = rsqrtf(var + EPS);
        v = (raw - m) * inv * g[o] + bb[o];
    }
    pin[idx] = v;
}

// ---------------- Depthwise 3x3 with per-patch weights + stats ----------------
// grid.x = B*C*(H*W/256); block = 256 (one 256-pixel chunk of one (b,c) plane)
__global__ void dw_kernel(const float* __restrict__ pin, const float* __restrict__ wsig,
                          float* __restrict__ out, float* __restrict__ stats,
                          int C, int H, int W, int WC) {
    int HW = H * W;
    int chunks = HW >> 8;
    int blk = blockIdx.x;
    int chunk = blk % chunks;
    int plane = blk / chunks;
    int c = plane % C, b = plane / C;
    int pix = (chunk << 8) + threadIdx.x;
    int h = pix / W, w = pix % W;
    int p = H >> 3, q = W >> 3;
    int u = h / p, v = w / q;
    const float* wb = wsig + (size_t)((b * WC + c * 9) << 6) + (u << 3) + v;
    const float* xb = pin + (size_t)plane * HW;
    float acc = 0.f;
#pragma unroll
    for (int t = 0; t < 9; ++t) {
        int di = t / 3 - 1, dj = t % 3 - 1;
        int hh = reflect_idx(h + di, H), ww = reflect_idx(w + dj, W);
        acc += wb[t << 6] * xb[hh * W + ww];
    }
    out[(size_t)plane * HW + pix] = acc;

    float s1 = acc, s2 = acc * acc;
#pragma unroll
    for (int off = 32; off; off >>= 1) {
        s1 += __shfl_xor(s1, off);
        s2 += __shfl_xor(s2, off);
    }
    __shared__ float ls1[4], ls2[4];
    int wave = threadIdx.x >> 6, lane = threadIdx.x & 63;
    if (lane == 0) { ls1[wave] = s1; ls2[wave] = s2; }
    __syncthreads();
    if (threadIdx.x == 0) {
        atomicAdd(&stats[2 * c],     ls1[0] + ls1[1] + ls1[2] + ls1[3]);
        atomicAdd(&stats[2 * c + 1], ls2[0] + ls2[1] + ls2[2] + ls2[3]);
    }
}

// ---------------- Pointwise 1x1 with per-patch weights, fused BN+ReLU6 on input, stats on output ----
// grid.x = B*(H*W/256); block = 256 (one 256-pixel chunk of batch b, all ONC out channels)
template <int ONC>
__global__ void pw_kernel(const float* __restrict__ dwraw, const float* __restrict__ wsig,
                          const float* __restrict__ dstats, const float* __restrict__ gdw,
                          const float* __restrict__ bdw,
                          float* __restrict__ out, float* __restrict__ ostats,
                          int C, int H, int W, int WC, int ndw, float invN) {
    int HW = H * W;
    int chunks = HW >> 8;
    int blk = blockIdx.x;
    int chunk = blk % chunks;
    int b = blk / chunks;
    int pix = (chunk << 8) + threadIdx.x;
    int h = pix / W, w = pix % W;
    int p = H >> 3, q = W >> 3;
    int u = h / p, v = w / q;

    __shared__ float ssc[128], ssh[128];
    for (int c = threadIdx.x; c < C; c += blockDim.x) {
        float m = dstats[2 * c] * invN;
        float var = dstats[2 * c + 1] * invN - m * m;
        float inv = rsqrtf(var + EPS);
        float s = gdw[c] * inv;
        ssc[c] = s;
        ssh[c] = bdw[c] - m * s;
    }
    __syncthreads();

    float acc[ONC];
#pragma unroll
    for (int o = 0; o < ONC; ++o) acc[o] = 0.f;

    const float* wbase = wsig + ((size_t)(b * WC + ndw) << 6) + (u << 3) + v;
    const float* xb = dwraw + (size_t)b * C * HW + pix;
    for (int c = 0; c < C; ++c) {
        float xv = xb[(size_t)c * HW];
        xv = fminf(fmaxf(xv * ssc[c] + ssh[c], 0.f), 6.f);
        const float* wc = wbase + ((size_t)c << 6);
#pragma unroll
        for (int o = 0; o < ONC; ++o)
            acc[o] += wc[(size_t)(o * C) << 6] * xv;
    }

    float* ob = out + (size_t)b * ONC * HW + pix;
#pragma unroll
    for (int o = 0; o < ONC; ++o) ob[(size_t)o * HW] = acc[o];

    int lane = threadIdx.x & 63;
#pragma unroll
    for (int o = 0; o < ONC; ++o) {
        float s1 = acc[o], s2 = acc[o] * acc[o];
#pragma unroll
        for (int off = 32; off; off >>= 1) {
            s1 += __shfl_xor(s1, off);
            s2 += __shfl_xor(s2, off);
        }
        if (lane == 0) {
            atomicAdd(&ostats[2 * o], s1);
            atomicAdd(&ostats[2 * o + 1], s2);
        }
    }
}

// ---------------- Final in-place BN on d_out @ 4x21x256x256 ----------------
__global__ void finalbn_kernel(float* __restrict__ out, const float* __restrict__ stats,
                               const float* __restrict__ g, const float* __restrict__ bb) {
    const int B = 4, C = 21, H = 256, W = 256;
    const float invN = 1.f / (B * H * W);
    int idx = blockIdx.x * blockDim.x + threadIdx.x;
    int total = B * C * H * W;
    if (idx >= total) return;
    int c = (idx / (H * W)) % C;
    float m = stats[2 * c] * invN;
    float var = stats[2 * c + 1] * invN - m * m;
    float inv = rsqrtf(var + EPS);
    out[idx] = (out[idx] - m) * inv * g[c] + bb[c];
}

extern "C" void kernel_launch(void* const* d_in, const int* in_sizes, int n_in,
                              void* d_out, int out_size, void* d_ws, size_t ws_size,
                              hipStream_t stream) {
    const float* x_img = (const float*)d_in[0];
    const float* f0    = (const float*)d_in[1];
    const float* f1    = (const float*)d_in[2];
    const float* w0    = (const float*)d_in[3];
    const float* w1    = (const float*)d_in[4];
    const float* w2    = (const float*)d_in[5];
    const float* g_dw0 = (const float*)d_in[6],  *b_dw0 = (const float*)d_in[7];
    const float* g_pw0 = (const float*)d_in[8],  *b_pw0 = (const float*)d_in[9];
    const float* g_dw1 = (const float*)d_in[10], *b_dw1 = (const float*)d_in[11];
    const float* g_pw1 = (const float*)d_in[12], *b_pw1 = (const float*)d_in[13];
    const float* g_dw2 = (const float*)d_in[14], *b_dw2 = (const float*)d_in[15];
    const float* g_pw2 = (const float*)d_in[16], *b_pw2 = (const float*)d_in[17];
    float* out = (float*)d_out;
    float* ws = (float*)d_ws;

    // workspace layout (floats)
    float* stats  = ws;            // 1024 total for all stats
    float* sdw0 = stats;           // 132
    float* spw0 = stats + 132;     // 128
    float* sdw1 = stats + 260;     // 196
    float* spw1 = stats + 456;     // 64
    float* sdw2 = stats + 520;     // 74
    float* spw2 = stats + 594;     // 42
    float* pw0raw = ws + 1024;           // 4*64*32*32   = 262144
    float* pw1raw = pw0raw + 262144;     // 4*32*64*64   = 524288
    float* bigA   = pw1raw + 524288;     // up to 4*37*256*256 = 9699328
    float* bigB   = bigA + 9699328;      // same size

    hipMemsetAsync(stats, 0, 1024 * sizeof(float), stream);

    // ---- Level 0: C=66, 32x32, out 64 ----
    build0_kernel<<<270336 / 256, 256, 0, stream>>>(f1, bigA);
    dw_kernel<<<4 * 66 * (1024 / 256), 256, 0, stream>>>(bigA, w0, bigB, sdw0, 66, 32, 32, 4818);
    pw_kernel<64><<<4 * (1024 / 256), 256, 0, stream>>>(bigB, w0, sdw0, g_dw0, b_dw0,
                                                        pw0raw, spw0, 66, 32, 32, 4818, 594,
                                                        1.f / 4096.f);
    // ---- Level 1: C=98, 64x64, out 32 ----
    build1_kernel<<<1605632 / 256, 256, 0, stream>>>(f0, pw0raw, spw0, g_pw0, b_pw0, bigA);
    dw_kernel<<<4 * 98 * (4096 / 256), 256, 0, stream>>>(bigA, w1, bigB, sdw1, 98, 64, 64, 4018);
    pw_kernel<32><<<4 * (4096 / 256), 256, 0, stream>>>(bigB, w1, sdw1, g_dw1, b_dw1,
                                                        pw1raw, spw1, 98, 64, 64, 4018, 882,
                                                        1.f / 16384.f);
    // ---- Level 2: C=37, 256x256, out 21 ----
    build2_kernel<<<9699328 / 256, 256, 0, stream>>>(x_img, pw1raw, spw1, g_pw1, b_pw1, bigA);
    dw_kernel<<<4 * 37 * (65536 / 256), 256, 0, stream>>>(bigA, w2, bigB, sdw2, 37, 256, 256, 1110);
    pw_kernel<21><<<4 * (65536 / 256), 256, 0, stream>>>(bigB, w2, sdw2, g_dw2, b_dw2,
                                                         out, spw2, 37, 256, 256, 1110, 333,
                                                         1.f / 262144.f);
    finalbn_kernel<<<5505024 / 256, 256, 0, stream>>>(out, spw2, g_pw2, b_pw2);
}

// Round 2
// 752.836 us; speedup vs baseline: 3.2070x; 3.2070x over previous
//
#include <hip/hip_runtime.h>

#define EPS 1e-5f

__device__ __forceinline__ int reflect_idx(int i, int n) {
    if (i < 0) return -i;
    if (i >= n) return 2 * n - 2 - i;
    return i;
}

// ---------------- Level-0 input build: [coords(2), f1(64)] @ 4x66x32x32 ----------------
__global__ void build0_kernel(const float* __restrict__ f1, float* __restrict__ pin) {
    const int B = 4, C = 66, H = 32, W = 32;
    int idx = blockIdx.x * blockDim.x + threadIdx.x;
    int total = B * C * H * W;
    if (idx >= total) return;
    int w = idx % W;
    int h = (idx / W) % H;
    int c = (idx / (W * H)) % C;
    int b = idx / (W * H * C);
    float v;
    if (c == 0)      v = -1.f + 2.f * w / (W - 1);
    else if (c == 1) v = -1.f + 2.f * h / (H - 1);
    else             v = f1[((b * 64 + (c - 2)) * H + h) * W + w];
    pin[idx] = v;
}

// ---------------- Level-1 input build: [coords(2), f0(32), BN(resize2x(pw0))(64)] @ 4x98x64x64 ----
__global__ void build1_kernel(const float* __restrict__ f0, const float* __restrict__ prev,
                              const float* __restrict__ pstats, const float* __restrict__ g,
                              const float* __restrict__ bb, float* __restrict__ pin) {
    const int B = 4, C = 98, H = 64, W = 64, Cf = 32, Hp = 32, Wp = 32, Cp = 64;
    const float invN = 1.f / (B * Hp * Wp);
    int idx = blockIdx.x * blockDim.x + threadIdx.x;
    int total = B * C * H * W;
    if (idx >= total) return;
    int w = idx % W;
    int h = (idx / W) % H;
    int c = (idx / (W * H)) % C;
    int b = idx / (W * H * C);
    float v;
    if (c == 0)      v = -1.f + 2.f * w / (W - 1);
    else if (c == 1) v = -1.f + 2.f * h / (H - 1);
    else if (c < 2 + Cf) v = f0[((b * Cf + (c - 2)) * H + h) * W + w];
    else {
        int o = c - 2 - Cf;
        float sy = (h + 0.5f) * 0.5f - 0.5f;
        float sx = (w + 0.5f) * 0.5f - 0.5f;
        int y0 = (int)floorf(sy), x0 = (int)floorf(sx);
        float fy = sy - y0, fx = sx - x0;
        int y0c = min(max(y0, 0), Hp - 1), y1c = min(max(y0 + 1, 0), Hp - 1);
        int x0c = min(max(x0, 0), Wp - 1), x1c = min(max(x0 + 1, 0), Wp - 1);
        const float* pb = prev + ((size_t)(b * Cp + o) * Hp) * Wp;
        float v00 = pb[y0c * Wp + x0c], v01 = pb[y0c * Wp + x1c];
        float v10 = pb[y1c * Wp + x0c], v11 = pb[y1c * Wp + x1c];
        float raw = v00 * (1 - fy) * (1 - fx) + v01 * (1 - fy) * fx
                  + v10 * fy * (1 - fx) + v11 * fy * fx;
        float m = pstats[2 * o] * invN;
        float var = pstats[2 * o + 1] * invN - m * m;
        float inv = rsqrtf(var + EPS);
        v = (raw - m) * inv * g[o] + bb[o];
    }
    pin[idx] = v;
}

// ---------------- Level-2 input build: [coords(2), x_img(3), BN(resize4x(pw1))(32)] @ 4x37x256x256 ----
__global__ void build2_kernel(const float* __restrict__ ximg, const float* __restrict__ prev,
                              const float* __restrict__ pstats, const float* __restrict__ g,
                              const float* __restrict__ bb, float* __restrict__ pin) {
    const int B = 4, C = 37, H = 256, W = 256, Cf = 3, Hp = 64, Wp = 64, Cp = 32;
    const float invN = 1.f / (B * Hp * Wp);
    int idx = blockIdx.x * blockDim.x + threadIdx.x;
    int total = B * C * H * W;
    if (idx >= total) return;
    int w = idx % W;
    int h = (idx / W) % H;
    int c = (idx / (W * H)) % C;
    int b = idx / (W * H * C);
    float v;
    if (c == 0)      v = -1.f + 2.f * w / (W - 1);
    else if (c == 1) v = -1.f + 2.f * h / (H - 1);
    else if (c < 2 + Cf) v = ximg[((b * Cf + (c - 2)) * H + h) * W + w];
    else {
        int o = c - 2 - Cf;
        float sy = (h + 0.5f) * 0.25f - 0.5f;
        float sx = (w + 0.5f) * 0.25f - 0.5f;
        int y0 = (int)floorf(sy), x0 = (int)floorf(sx);
        float fy = sy - y0, fx = sx - x0;
        int y0c = min(max(y0, 0), Hp - 1), y1c = min(max(y0 + 1, 0), Hp - 1);
        int x0c = min(max(x0, 0), Wp - 1), x1c = min(max(x0 + 1, 0), Wp - 1);
        const float* pb = prev + ((size_t)(b * Cp + o) * Hp) * Wp;
        float v00 = pb[y0c * Wp + x0c], v01 = pb[y0c * Wp + x1c];
        float v10 = pb[y1c * Wp + x0c], v11 = pb[y1c * Wp + x1c];
        float raw = v00 * (1 - fy) * (1 - fx) + v01 * (1 - fy) * fx
                  + v10 * fy * (1 - fx) + v11 * fy * fx;
        float m = pstats[2 * o] * invN;
        float var = pstats[2 * o + 1] * invN - m * m;
        float inv = rsqrtf(var + EPS);
        v = (raw - m) * inv * g[o] + bb[o];
    }
    pin[idx] = v;
}

// ---------------- Depthwise 3x3 with per-patch weights + stats ----------------
__global__ void dw_kernel(const float* __restrict__ pin, const float* __restrict__ wsig,
                          float* __restrict__ out, float* __restrict__ stats,
                          int C, int H, int W, int WC) {
    int HW = H * W;
    int chunks = HW >> 8;
    int blk = blockIdx.x;
    int chunk = blk % chunks;
    int plane = blk / chunks;
    int c = plane % C, b = plane / C;
    int pix = (chunk << 8) + threadIdx.x;
    int h = pix / W, w = pix % W;
    int p = H >> 3, q = W >> 3;
    int u = h / p, v = w / q;
    const float* wb = wsig + (size_t)((b * WC + c * 9) << 6) + (u << 3) + v;
    const float* xb = pin + (size_t)plane * HW;
    float acc = 0.f;
#pragma unroll
    for (int t = 0; t < 9; ++t) {
        int di = t / 3 - 1, dj = t % 3 - 1;
        int hh = reflect_idx(h + di, H), ww = reflect_idx(w + dj, W);
        acc += wb[t << 6] * xb[hh * W + ww];
    }
    out[(size_t)plane * HW + pix] = acc;

    float s1 = acc, s2 = acc * acc;
#pragma unroll
    for (int off = 32; off; off >>= 1) {
        s1 += __shfl_xor(s1, off);
        s2 += __shfl_xor(s2, off);
    }
    __shared__ float ls1[4], ls2[4];
    int wave = threadIdx.x >> 6, lane = threadIdx.x & 63;
    if (lane == 0) { ls1[wave] = s1; ls2[wave] = s2; }
    __syncthreads();
    if (threadIdx.x == 0) {
        atomicAdd(&stats[2 * c],     ls1[0] + ls1[1] + ls1[2] + ls1[3]);
        atomicAdd(&stats[2 * c + 1], ls2[0] + ls2[1] + ls2[2] + ls2[3]);
    }
}

// ---------------- Pointwise 1x1: weights in LDS, per-patch blocks ----------------
// Block decomposition: grid = B * 64 * CHUNKS. Threads = PX_T px-threads x OC_T oc-threads.
template <int C, int ONC, int H, int W, int PX_T, int OC_T, int CHUNKS>
__global__ __launch_bounds__(256)
void pw_lds_kernel(const float* __restrict__ dwraw, const float* __restrict__ wsig,
                   const float* __restrict__ dstats, const float* __restrict__ gdw,
                   const float* __restrict__ bdw, float* __restrict__ out,
                   float* __restrict__ ostats, int WC, int ndw, float invN) {
    constexpr int P = H / 8, Q = W / 8;
    constexpr int OC_I = ONC / OC_T;
    constexpr int XSZ = (OC_T > 1) ? C * PX_T : 1;
    __shared__ float lw[ONC * C];
    __shared__ float ssc[C], ssh[C];
    __shared__ float lx[XSZ];

    int tid = threadIdx.x;
    int bid = blockIdx.x;
    int chunk = (CHUNKS > 1) ? (bid % CHUNKS) : 0;
    int uv = (bid / CHUNKS) & 63;
    int b = bid / (CHUNKS * 64);
    int u = uv >> 3, v = uv & 7;

    for (int c = tid; c < C; c += 256) {
        float m = dstats[2 * c] * invN;
        float var = dstats[2 * c + 1] * invN - m * m;
        float inv = rsqrtf(var + EPS);
        float s = gdw[c] * inv;
        ssc[c] = s;
        ssh[c] = bdw[c] - m * s;
    }
    const size_t wbase = ((size_t)b * WC + ndw) * 64 + uv;
    for (int i = tid; i < ONC * C; i += 256) lw[i] = wsig[wbase + (size_t)i * 64];
    __syncthreads();

    if constexpr (OC_T > 1) {
        for (int i = tid; i < C * PX_T; i += 256) {
            int c = i / PX_T, pxl = i % PX_T;
            int h = u * P + pxl / Q, w = v * Q + pxl % Q;
            float xv = dwraw[(((size_t)b * C + c) * H + h) * W + w];
            lx[i] = fminf(fmaxf(xv * ssc[c] + ssh[c], 0.f), 6.f);
        }
        __syncthreads();
    }

    int px_id = tid % PX_T, oc_id = tid / PX_T;
    int l = chunk * PX_T + px_id;
    int h = u * P + l / Q, w = v * Q + l % Q;

    float acc[OC_I];
#pragma unroll
    for (int oi = 0; oi < OC_I; ++oi) acc[oi] = 0.f;

    const float* xg = dwraw + (((size_t)b * C) * H + h) * W + w;

    for (int c = 0; c < C; ++c) {
        float xv;
        if constexpr (OC_T > 1) {
            xv = lx[c * PX_T + px_id];
        } else {
            xv = xg[(size_t)c * H * W];
            xv = fminf(fmaxf(xv * ssc[c] + ssh[c], 0.f), 6.f);
        }
#pragma unroll
        for (int oi = 0; oi < OC_I; ++oi)
            acc[oi] += lw[(oc_id * OC_I + oi) * C + c] * xv;
    }

    float* ob = out + (((size_t)b * ONC) * H + h) * W + w;
#pragma unroll
    for (int oi = 0; oi < OC_I; ++oi)
        ob[(size_t)(oc_id * OC_I + oi) * H * W] = acc[oi];

    // stats
    int lane = tid & 63;
    if constexpr (OC_T == 1) {
        __shared__ float red1[4][ONC], red2[4][ONC];
        int wave = tid >> 6;
#pragma unroll
        for (int oi = 0; oi < OC_I; ++oi) {
            float s1 = acc[oi], s2 = acc[oi] * acc[oi];
#pragma unroll
            for (int off = 32; off; off >>= 1) {
                s1 += __shfl_xor(s1, off);
                s2 += __shfl_xor(s2, off);
            }
            if (lane == 0) { red1[wave][oi] = s1; red2[wave][oi] = s2; }
        }
        __syncthreads();
        for (int o = tid; o < ONC; o += 256) {
            atomicAdd(&ostats[2 * o],     red1[0][o] + red1[1][o] + red1[2][o] + red1[3][o]);
            atomicAdd(&ostats[2 * o + 1], red2[0][o] + red2[1][o] + red2[2][o] + red2[3][o]);
        }
    } else {
        constexpr int GROUP = (PX_T < 64) ? PX_T : 64;
#pragma unroll
        for (int oi = 0; oi < OC_I; ++oi) {
            float s1 = acc[oi], s2 = acc[oi] * acc[oi];
#pragma unroll
            for (int off = GROUP / 2; off; off >>= 1) {
                s1 += __shfl_xor(s1, off);
                s2 += __shfl_xor(s2, off);
            }
            if ((lane & (GROUP - 1)) == 0) {
                int o = oc_id * OC_I + oi;
                atomicAdd(&ostats[2 * o], s1);
                atomicAdd(&ostats[2 * o + 1], s2);
            }
        }
    }
}

// ---------------- Final in-place BN on d_out @ 4x21x256x256 ----------------
__global__ void finalbn_kernel(float* __restrict__ out, const float* __restrict__ stats,
                               const float* __restrict__ g, const float* __restrict__ bb) {
    const int B = 4, C = 21, H = 256, W = 256;
    const float invN = 1.f / (B * H * W);
    int idx = blockIdx.x * blockDim.x + threadIdx.x;
    int total = B * C * H * W;
    if (idx >= total) return;
    int c = (idx / (H * W)) % C;
    float m = stats[2 * c] * invN;
    float var = stats[2 * c + 1] * invN - m * m;
    float inv = rsqrtf(var + EPS);
    out[idx] = (out[idx] - m) * inv * g[c] + bb[c];
}

extern "C" void kernel_launch(void* const* d_in, const int* in_sizes, int n_in,
                              void* d_out, int out_size, void* d_ws, size_t ws_size,
                              hipStream_t stream) {
    const float* x_img = (const float*)d_in[0];
    const float* f0    = (const float*)d_in[1];
    const float* f1    = (const float*)d_in[2];
    const float* w0    = (const float*)d_in[3];
    const float* w1    = (const float*)d_in[4];
    const float* w2    = (const float*)d_in[5];
    const float* g_dw0 = (const float*)d_in[6],  *b_dw0 = (const float*)d_in[7];
    const float* g_pw0 = (const float*)d_in[8],  *b_pw0 = (const float*)d_in[9];
    const float* g_dw1 = (const float*)d_in[10], *b_dw1 = (const float*)d_in[11];
    const float* g_pw1 = (const float*)d_in[12], *b_pw1 = (const float*)d_in[13];
    const float* g_dw2 = (const float*)d_in[14], *b_dw2 = (const float*)d_in[15];
    const float* g_pw2 = (const float*)d_in[16], *b_pw2 = (const float*)d_in[17];
    float* out = (float*)d_out;
    float* ws = (float*)d_ws;

    // workspace layout (floats)
    float* stats  = ws;            // 1024 total for all stats
    float* sdw0 = stats;           // 132
    float* spw0 = stats + 132;     // 128
    float* sdw1 = stats + 260;     // 196
    float* spw1 = stats + 456;     // 64
    float* sdw2 = stats + 520;     // 74
    float* spw2 = stats + 594;     // 42
    float* pw0raw = ws + 1024;           // 4*64*32*32   = 262144
    float* pw1raw = pw0raw + 262144;     // 4*32*64*64   = 524288
    float* bigA   = pw1raw + 524288;     // up to 4*37*256*256 = 9699328
    float* bigB   = bigA + 9699328;      // same size

    hipMemsetAsync(stats, 0, 1024 * sizeof(float), stream);

    // ---- Level 0: C=66, 32x32, out 64 ----
    build0_kernel<<<270336 / 256, 256, 0, stream>>>(f1, bigA);
    dw_kernel<<<4 * 66 * (1024 / 256), 256, 0, stream>>>(bigA, w0, bigB, sdw0, 66, 32, 32, 4818);
    pw_lds_kernel<66, 64, 32, 32, 16, 16, 1><<<256, 256, 0, stream>>>(
        bigB, w0, sdw0, g_dw0, b_dw0, pw0raw, spw0, 4818, 594, 1.f / 4096.f);
    // ---- Level 1: C=98, 64x64, out 32 ----
    build1_kernel<<<1605632 / 256, 256, 0, stream>>>(f0, pw0raw, spw0, g_pw0, b_pw0, bigA);
    dw_kernel<<<4 * 98 * (4096 / 256), 256, 0, stream>>>(bigA, w1, bigB, sdw1, 98, 64, 64, 4018);
    pw_lds_kernel<98, 32, 64, 64, 64, 4, 1><<<256, 256, 0, stream>>>(
        bigB, w1, sdw1, g_dw1, b_dw1, pw1raw, spw1, 4018, 882, 1.f / 16384.f);
    // ---- Level 2: C=37, 256x256, out 21 ----
    build2_kernel<<<9699328 / 256, 256, 0, stream>>>(x_img, pw1raw, spw1, g_pw1, b_pw1, bigA);
    dw_kernel<<<4 * 37 * (65536 / 256), 256, 0, stream>>>(bigA, w2, bigB, sdw2, 37, 256, 256, 1110);
    pw_lds_kernel<37, 21, 256, 256, 256, 1, 4><<<1024, 256, 0, stream>>>(
        bigB, w2, sdw2, g_dw2, b_dw2, out, spw2, 1110, 333, 1.f / 262144.f);
    finalbn_kernel<<<5505024 / 256, 256, 0, stream>>>(out, spw2, g_pw2, b_pw2);
}

// Round 3
// 145.695 us; speedup vs baseline: 16.5714x; 5.1672x over previous
//
#include <hip/hip_runtime.h>

#define EPS 1e-5f

__device__ __forceinline__ int reflect_idx(int i, int n) {
    if (i < 0) return -i;
    if (i >= n) return 2 * n - 2 - i;
    return i;
}

__device__ __forceinline__ float bilin(const float* __restrict__ pb, int Hp, float sy, float sx) {
    int y0 = (int)floorf(sy), x0 = (int)floorf(sx);
    float fy = sy - y0, fx = sx - x0;
    int y0c = min(max(y0, 0), Hp - 1), y1c = min(max(y0 + 1, 0), Hp - 1);
    int x0c = min(max(x0, 0), Hp - 1), x1c = min(max(x0 + 1, 0), Hp - 1);
    float v00 = pb[y0c * Hp + x0c], v01 = pb[y0c * Hp + x1c];
    float v10 = pb[y1c * Hp + x0c], v11 = pb[y1c * Hp + x1c];
    return v00 * (1 - fy) * (1 - fx) + v01 * (1 - fy) * fx
         + v10 * fy * (1 - fx) + v11 * fy * fx;
}

// ---------------- Fused build + depthwise 3x3 + striped stats ----------------
// One block = one (b, c, tile). Halo of built input staged in LDS (build is
// pointwise, reflect applied to coordinates). Branch on c is block-uniform.
template <int LEVEL>
__global__ __launch_bounds__(256)
void fused_dw_kernel(const float* __restrict__ feat, const float* __restrict__ prev,
                     const float* __restrict__ pss, const float* __restrict__ wsig,
                     float* __restrict__ out, float* __restrict__ part) {
    constexpr int C    = LEVEL == 0 ? 66 : LEVEL == 1 ? 98 : 37;
    constexpr int H    = LEVEL == 0 ? 32 : LEVEL == 1 ? 64 : 256;
    constexpr int TILE = LEVEL == 2 ? 32 : 16;
    constexpr int NT   = H / TILE;
    constexpr int PXPT = (TILE * TILE) / 256;
    constexpr int WC   = LEVEL == 0 ? 4818 : LEVEL == 1 ? 4018 : 1110;
    constexpr int NF   = LEVEL == 0 ? 64 : LEVEL == 1 ? 32 : 3;
    constexpr int Hp   = LEVEL == 1 ? 32 : 64;
    constexpr int Cp   = LEVEL == 1 ? 64 : 32;
    constexpr int P    = H / 8;
    constexpr float SC = LEVEL == 1 ? 0.5f : 0.25f;
    constexpr int HS   = TILE + 2;

    __shared__ float sh[HS * HS];
    int tid = threadIdx.x, bid = blockIdx.x;
    int tile = bid % (NT * NT);
    int c = (bid / (NT * NT)) % C;
    int b = bid / (NT * NT * C);
    int ty0 = (tile / NT) * TILE, tx0 = (tile % NT) * TILE;

    for (int i = tid; i < HS * HS; i += 256) {
        int h = reflect_idx(ty0 - 1 + i / HS, H);
        int w = reflect_idx(tx0 - 1 + i % HS, H);
        float val;
        if (c == 0)      val = -1.f + 2.f * w / (H - 1);
        else if (c == 1) val = -1.f + 2.f * h / (H - 1);
        else if (c < 2 + NF) val = feat[((size_t)(b * NF + c - 2) * H + h) * H + w];
        else {
            int o = c - 2 - NF;
            const float* pb = prev + (size_t)(b * Cp + o) * Hp * Hp;
            float raw = bilin(pb, Hp, (h + 0.5f) * SC - 0.5f, (w + 0.5f) * SC - 0.5f);
            val = raw * pss[2 * o] + pss[2 * o + 1];
        }
        sh[i] = val;
    }
    __syncthreads();

    float s1 = 0.f, s2 = 0.f;
    float* ob = out + (((size_t)(b * C + c)) * H + ty0) * H + tx0;
    float wreg[9];
    if constexpr (TILE == P) {
        const float* wb = wsig + ((size_t)(b * WC + c * 9)) * 64 + (ty0 / P) * 8 + (tx0 / P);
#pragma unroll
        for (int t = 0; t < 9; ++t) wreg[t] = wb[(size_t)t * 64];
    }
#pragma unroll
    for (int k = 0; k < PXPT; ++k) {
        int px = tid + k * 256;
        int tyy = px / TILE, txx = px % TILE;
        if constexpr (TILE != P) {
            int u = (ty0 + tyy) / P, vv = (tx0 + txx) / P;
            const float* wb = wsig + ((size_t)(b * WC + c * 9)) * 64 + u * 8 + vv;
#pragma unroll
            for (int t = 0; t < 9; ++t) wreg[t] = wb[(size_t)t * 64];
        }
        float acc = 0.f;
#pragma unroll
        for (int t = 0; t < 9; ++t)
            acc += wreg[t] * sh[(tyy + t / 3) * HS + txx + t % 3];
        ob[tyy * H + txx] = acc;
        s1 += acc; s2 += acc * acc;
    }
#pragma unroll
    for (int off = 32; off; off >>= 1) {
        s1 += __shfl_xor(s1, off);
        s2 += __shfl_xor(s2, off);
    }
    __shared__ float r1[4], r2[4];
    int wave = tid >> 6;
    if ((tid & 63) == 0) { r1[wave] = s1; r2[wave] = s2; }
    __syncthreads();
    if (tid == 0) {
        int slot = bid & 63;
        atomicAdd(&part[slot * 2 * C + 2 * c],     r1[0] + r1[1] + r1[2] + r1[3]);
        atomicAdd(&part[slot * 2 * C + 2 * c + 1], r2[0] + r2[1] + r2[2] + r2[3]);
    }
}

// ---------------- Reduce 64-slot partials -> per-channel (scale, shift) ----------------
__global__ void red_kernel(const float* __restrict__ part, const float* __restrict__ g,
                           const float* __restrict__ bb, float* __restrict__ ss,
                           int C, float invN) {
    int c = threadIdx.x;
    if (c >= C) return;
    float s1 = 0.f, s2 = 0.f;
    for (int s = 0; s < 64; ++s) {
        s1 += part[s * 2 * C + 2 * c];
        s2 += part[s * 2 * C + 2 * c + 1];
    }
    float m = s1 * invN;
    float var = s2 * invN - m * m;
    float sc = g[c] * rsqrtf(var + EPS);
    ss[2 * c] = sc;
    ss[2 * c + 1] = bb[c] - m * sc;
}

// ---------------- Pointwise 1x1, small levels (patch px <= 64) ----------------
template <int C, int ONC, int H, int PX_T, int OC_T>
__global__ __launch_bounds__(256)
void pw_small_kernel(const float* __restrict__ x, const float* __restrict__ wsig,
                     const float* __restrict__ ss, float* __restrict__ out,
                     float* __restrict__ part, int WC, int ndw) {
    constexpr int P = H / 8;
    constexpr int OC_I = ONC / OC_T;
    __shared__ float lw[ONC * C];
    __shared__ float lx[C * PX_T];
    int tid = threadIdx.x, bid = blockIdx.x;
    int uv = bid & 63, b = bid >> 6;
    int u = uv >> 3, v = uv & 7;

    const size_t wbase = ((size_t)b * WC + ndw) * 64 + uv;
    for (int i = tid; i < ONC * C; i += 256) lw[i] = wsig[wbase + (size_t)i * 64];
    for (int i = tid; i < C * PX_T; i += 256) {
        int c = i / PX_T, pxl = i % PX_T;
        int h = u * P + pxl / P, w = v * P + pxl % P;
        float xv = x[(((size_t)b * C + c) * H + h) * H + w];
        lx[i] = fminf(fmaxf(xv * ss[2 * c] + ss[2 * c + 1], 0.f), 6.f);
    }
    __syncthreads();

    int px_id = tid % PX_T, oc_id = tid / PX_T;
    int h = u * P + px_id / P, w = v * P + px_id % P;
    float acc[OC_I];
#pragma unroll
    for (int oi = 0; oi < OC_I; ++oi) acc[oi] = 0.f;
    for (int c = 0; c < C; ++c) {
        float xv = lx[c * PX_T + px_id];
#pragma unroll
        for (int oi = 0; oi < OC_I; ++oi)
            acc[oi] += lw[(oc_id * OC_I + oi) * C + c] * xv;
    }
    float* ob = out + (((size_t)b * ONC) * H + h) * H + w;
#pragma unroll
    for (int oi = 0; oi < OC_I; ++oi)
        ob[(size_t)(oc_id * OC_I + oi) * H * H] = acc[oi];

    constexpr int GROUP = (PX_T < 64) ? PX_T : 64;
    int lane = tid & 63;
    int slot = bid & 63;
#pragma unroll
    for (int oi = 0; oi < OC_I; ++oi) {
        float s1 = acc[oi], s2 = acc[oi] * acc[oi];
#pragma unroll
        for (int off = GROUP / 2; off; off >>= 1) {
            s1 += __shfl_xor(s1, off);
            s2 += __shfl_xor(s2, off);
        }
        if ((lane & (GROUP - 1)) == 0) {
            int o = oc_id * OC_I + oi;
            atomicAdd(&part[slot * 2 * ONC + 2 * o], s1);
            atomicAdd(&part[slot * 2 * ONC + 2 * o + 1], s2);
        }
    }
}

// ---------------- Pointwise 1x1 level 2: float4, one patch per block ----------------
__global__ __launch_bounds__(256)
void pw2_kernel(const float* __restrict__ x, const float* __restrict__ wsig,
                const float* __restrict__ ss, float* __restrict__ out,
                float* __restrict__ part) {
    const int C = 37, ONC = 21, H = 256, PATCH = 32, WC = 1110, NDW = 333;
    __shared__ float lw[ONC * C];
    __shared__ float lsc[C], lsh[C];
    __shared__ float r1[4][ONC], r2[4][ONC];
    int tid = threadIdx.x, bid = blockIdx.x;
    int uv = bid & 63, b = bid >> 6;
    int y0 = (uv >> 3) * PATCH, x0 = (uv & 7) * PATCH;

    for (int i = tid; i < ONC * C; i += 256) lw[i] = wsig[((size_t)(b * WC + NDW) + i) * 64 + uv];
    for (int c = tid; c < C; c += 256) { lsc[c] = ss[2 * c]; lsh[c] = ss[2 * c + 1]; }
    __syncthreads();

    int row = tid >> 3, col = (tid & 7) * 4;
    const float* xb = x + (((size_t)b * C) * H + y0 + row) * H + x0 + col;
    float4 acc[ONC];
#pragma unroll
    for (int o = 0; o < ONC; ++o) acc[o] = make_float4(0.f, 0.f, 0.f, 0.f);

    for (int c = 0; c < C; ++c) {
        float4 xv = *(const float4*)(xb + (size_t)c * H * H);
        float sc = lsc[c], sb = lsh[c];
        xv.x = fminf(fmaxf(xv.x * sc + sb, 0.f), 6.f);
        xv.y = fminf(fmaxf(xv.y * sc + sb, 0.f), 6.f);
        xv.z = fminf(fmaxf(xv.z * sc + sb, 0.f), 6.f);
        xv.w = fminf(fmaxf(xv.w * sc + sb, 0.f), 6.f);
#pragma unroll
        for (int o = 0; o < ONC; ++o) {
            float wv = lw[o * C + c];
            acc[o].x += wv * xv.x;
            acc[o].y += wv * xv.y;
            acc[o].z += wv * xv.z;
            acc[o].w += wv * xv.w;
        }
    }
    float* ob = out + (((size_t)b * ONC) * H + y0 + row) * H + x0 + col;
#pragma unroll
    for (int o = 0; o < ONC; ++o) *(float4*)(ob + (size_t)o * H * H) = acc[o];

    int wave = tid >> 6, lane = tid & 63;
#pragma unroll
    for (int o = 0; o < ONC; ++o) {
        float s1 = acc[o].x + acc[o].y + acc[o].z + acc[o].w;
        float s2 = acc[o].x * acc[o].x + acc[o].y * acc[o].y
                 + acc[o].z * acc[o].z + acc[o].w * acc[o].w;
#pragma unroll
        for (int off = 32; off; off >>= 1) {
            s1 += __shfl_xor(s1, off);
            s2 += __shfl_xor(s2, off);
        }
        if (lane == 0) { r1[wave][o] = s1; r2[wave][o] = s2; }
    }
    __syncthreads();
    int slot = bid & 63;
    for (int o = tid; o < ONC; o += 256) {
        atomicAdd(&part[slot * 2 * ONC + 2 * o],     r1[0][o] + r1[1][o] + r1[2][o] + r1[3][o]);
        atomicAdd(&part[slot * 2 * ONC + 2 * o + 1], r2[0][o] + r2[1][o] + r2[2][o] + r2[3][o]);
    }
}

// ---------------- Final in-place BN (float4) ----------------
__global__ void finalbn_kernel(float* __restrict__ out, const float* __restrict__ ss) {
    int idx = blockIdx.x * 256 + threadIdx.x;
    const int total4 = 4 * 21 * 256 * 256 / 4;
    if (idx >= total4) return;
    int c = (idx / (256 * 256 / 4)) % 21;
    float4 v = ((float4*)out)[idx];
    float sc = ss[2 * c], sb = ss[2 * c + 1];
    v.x = v.x * sc + sb; v.y = v.y * sc + sb; v.z = v.z * sc + sb; v.w = v.w * sc + sb;
    ((float4*)out)[idx] = v;
}

extern "C" void kernel_launch(void* const* d_in, const int* in_sizes, int n_in,
                              void* d_out, int out_size, void* d_ws, size_t ws_size,
                              hipStream_t stream) {
    const float* x_img = (const float*)d_in[0];
    const float* f0    = (const float*)d_in[1];
    const float* f1    = (const float*)d_in[2];
    const float* w0    = (const float*)d_in[3];
    const float* w1    = (const float*)d_in[4];
    const float* w2    = (const float*)d_in[5];
    const float* g_dw0 = (const float*)d_in[6],  *b_dw0 = (const float*)d_in[7];
    const float* g_pw0 = (const float*)d_in[8],  *b_pw0 = (const float*)d_in[9];
    const float* g_dw1 = (const float*)d_in[10], *b_dw1 = (const float*)d_in[11];
    const float* g_pw1 = (const float*)d_in[12], *b_pw1 = (const float*)d_in[13];
    const float* g_dw2 = (const float*)d_in[14], *b_dw2 = (const float*)d_in[15];
    const float* g_pw2 = (const float*)d_in[16], *b_pw2 = (const float*)d_in[17];
    float* out = (float*)d_out;
    float* ws = (float*)d_ws;

    // workspace layout (floats)
    float* part_dw0 = ws;              // 64*132 = 8448
    float* part_pw0 = ws + 8448;       // 64*128 = 8192
    float* part_dw1 = ws + 16640;      // 64*196 = 12544
    float* part_pw1 = ws + 29184;      // 64*64  = 4096
    float* part_dw2 = ws + 33280;      // 64*74  = 4736
    float* part_pw2 = ws + 38016;      // 64*42  = 2688  -> parts end 40704
    float* dw0ss = ws + 40704;         // 132
    float* pw0ss = ws + 40836;         // 128
    float* dw1ss = ws + 40964;         // 196
    float* pw1ss = ws + 41160;         // 64
    float* dw2ss = ws + 41224;         // 74
    float* pw2ss = ws + 41298;         // 42 -> 41340
    float* pw0raw = ws + 41344;        // 4*64*32*32 = 262144
    float* pw1raw = pw0raw + 262144;   // 4*32*64*64 = 524288
    float* bigA   = pw1raw + 524288;   // dw raw, up to 4*37*256*256 = 9699328

    hipMemsetAsync(ws, 0, 40704 * sizeof(float), stream);

    // ---- Level 0: C=66, 32x32, out 64 ----
    fused_dw_kernel<0><<<4 * 66 * 4, 256, 0, stream>>>(f1, nullptr, nullptr, w0, bigA, part_dw0);
    red_kernel<<<1, 128, 0, stream>>>(part_dw0, g_dw0, b_dw0, dw0ss, 66, 1.f / 4096.f);
    pw_small_kernel<66, 64, 32, 16, 16><<<256, 256, 0, stream>>>(
        bigA, w0, dw0ss, pw0raw, part_pw0, 4818, 594);
    red_kernel<<<1, 128, 0, stream>>>(part_pw0, g_pw0, b_pw0, pw0ss, 64, 1.f / 4096.f);
    // ---- Level 1: C=98, 64x64, out 32 ----
    fused_dw_kernel<1><<<4 * 98 * 16, 256, 0, stream>>>(f0, pw0raw, pw0ss, w1, bigA, part_dw1);
    red_kernel<<<1, 128, 0, stream>>>(part_dw1, g_dw1, b_dw1, dw1ss, 98, 1.f / 16384.f);
    pw_small_kernel<98, 32, 64, 64, 4><<<256, 256, 0, stream>>>(
        bigA, w1, dw1ss, pw1raw, part_pw1, 4018, 882);
    red_kernel<<<1, 128, 0, stream>>>(part_pw1, g_pw1, b_pw1, pw1ss, 32, 1.f / 16384.f);
    // ---- Level 2: C=37, 256x256, out 21 ----
    fused_dw_kernel<2><<<4 * 37 * 64, 256, 0, stream>>>(x_img, pw1raw, pw1ss, w2, bigA, part_dw2);
    red_kernel<<<1, 128, 0, stream>>>(part_dw2, g_dw2, b_dw2, dw2ss, 37, 1.f / 262144.f);
    pw2_kernel<<<256, 256, 0, stream>>>(bigA, w2, dw2ss, out, part_pw2);
    red_kernel<<<1, 128, 0, stream>>>(part_pw2, g_pw2, b_pw2, pw2ss, 21, 1.f / 262144.f);
    finalbn_kernel<<<5376, 256, 0, stream>>>(out, pw2ss);
}